// Round 12
// baseline (73.174 us; speedup 1.0000x reference)
//
#include <hip/hip_runtime.h>
#include <hip/hip_bf16.h>

typedef __attribute__((ext_vector_type(4))) float f32x4;
typedef __attribute__((ext_vector_type(8))) __bf16 bf16x8;
typedef __attribute__((ext_vector_type(8))) unsigned short ushort8;

__device__ __forceinline__ unsigned short f2bf(float f) {
    unsigned u = __builtin_bit_cast(unsigned, f);
    unsigned lsb = (u >> 16) & 1u;
    u += 0x7fffu + lsb;
    return (unsigned short)(u >> 16);
}

__device__ __forceinline__ f32x4 mfma16(ushort8 a, ushort8 b, f32x4 c) {
    return __builtin_amdgcn_mfma_f32_16x16x32_bf16(
        __builtin_bit_cast(bf16x8, a), __builtin_bit_cast(bf16x8, b), c, 0, 0, 0);
}

__device__ __forceinline__ void gload_lds16(const unsigned short* g, unsigned short* l) {
    __builtin_amdgcn_global_load_lds(
        (const __attribute__((address_space(1))) unsigned int*)g,
        (__attribute__((address_space(3))) unsigned int*)l, 16, 0, 0);
}

// ---------------- fused f32 -> bf16 convert, 32B/thread: x, wq, wk, wv, wo ----------
__global__ __launch_bounds__(256) void cvt_all_kernel(
    const float* __restrict__ x, const float* __restrict__ wq, const float* __restrict__ wk,
    const float* __restrict__ wv, const float* __restrict__ wo, unsigned short* __restrict__ dst) {
    int i = blockIdx.x * blockDim.x + threadIdx.x;  // float4-PAIR index, total 786432
    const float* src;
    size_t off;
    if (i < 262144) { src = x; off = i; }
    else {
        int j = i - 262144;
        int w = j >> 17;
        off = (size_t)(j & 131071);
        src = (w == 0) ? wq : (w == 1) ? wk : (w == 2) ? wv : wo;
    }
    float4 a = ((const float4*)src)[off * 2];
    float4 b = ((const float4*)src)[off * 2 + 1];
    ushort8 o;
    o[0] = f2bf(a.x); o[1] = f2bf(a.y); o[2] = f2bf(a.z); o[3] = f2bf(a.w);
    o[4] = f2bf(b.x); o[5] = f2bf(b.y); o[6] = f2bf(b.z); o[7] = f2bf(b.w);
    *(ushort8*)&dst[(size_t)i * 8] = o;
}

// ---------------- bt-GEMM qkv: 128x64 tile, 2 WAVES (128 thr), wave tile 64x64 acc4x4.
// BK=64, 2-phase dbuf, both-sides swizzle, XCD block swizzle. 48KB LDS -> 3 blocks/CU,
// 768 blocks = 3/CU balanced. Per-CU LDS reads now balance the MFMA pipe (8 reads:16 MFMA).
__global__ __launch_bounds__(128) void gemm_qkv(
    const unsigned short* __restrict__ xb,
    const unsigned short* __restrict__ wqb, const unsigned short* __restrict__ wkb,
    const unsigned short* __restrict__ wvb,
    const float* __restrict__ bq, const float* __restrict__ bk, const float* __restrict__ bv,
    unsigned short* __restrict__ qo, unsigned short* __restrict__ ko, unsigned short* __restrict__ vt) {
    const int N = 1024, K = 1024;
    int flat = blockIdx.x + 16 * blockIdx.y + 256 * blockIdx.z;   // 768 blocks
    int vid = (flat & 7) * 96 + (flat >> 3);                      // XCD-contiguous
    int bx = vid & 15, by = (vid >> 4) & 15, bz = vid >> 8;
    const unsigned short* Bt = (bz == 0) ? wqb : (bz == 1) ? wkb : wvb;
    const float* bias = (bz == 0) ? bq : (bz == 1) ? bk : bv;

    __shared__ unsigned short As[2][128 * 64];
    __shared__ unsigned short Bs[2][64 * 64];
    int tid = threadIdx.x;
    int wave = tid >> 6, lane = tid & 63;
    int lr = lane & 15, lk = lane >> 4;
    int m0 = bx * 128, n0 = by * 64;

    f32x4 acc[4][4] = {};

    auto stage = [&](int p, int kk) {
#pragma unroll
        for (int i = 0; i < 8; ++i) {
            int c = tid + 128 * i;
            int r = c >> 3, s = c & 7;
            gload_lds16(xb + (size_t)(m0 + r) * K + kk + (s ^ (r & 7)) * 8, &As[p][c * 8]);
        }
#pragma unroll
        for (int i = 0; i < 4; ++i) {
            int c = tid + 128 * i;
            int r = c >> 3, s = c & 7;
            gload_lds16(Bt + (size_t)(n0 + r) * K + kk + (s ^ (r & 7)) * 8, &Bs[p][c * 8]);
        }
    };

    stage(0, 0);
    asm volatile("s_waitcnt vmcnt(0)" ::: "memory");
    __syncthreads();

    for (int t = 0; t < 16; ++t) {
        int p = t & 1;
        if (t < 15) stage(p ^ 1, (t + 1) * 64);
#pragma unroll
        for (int ks = 0; ks < 2; ++ks) {
            ushort8 af[4], bfr[4];
#pragma unroll
            for (int f = 0; f < 4; ++f) {
                int row = wave * 64 + f * 16 + lr;
                int cc = ks * 4 + lk;
                af[f] = *(const ushort8*)&As[p][row * 64 + ((cc ^ (row & 7)) * 8)];
            }
#pragma unroll
            for (int f = 0; f < 4; ++f) {
                int row = f * 16 + lr;
                int cc = ks * 4 + lk;
                bfr[f] = *(const ushort8*)&Bs[p][row * 64 + ((cc ^ (row & 7)) * 8)];
            }
#pragma unroll
            for (int i = 0; i < 4; ++i)
#pragma unroll
                for (int j = 0; j < 4; ++j)
                    acc[i][j] = mfma16(af[i], bfr[j], acc[i][j]);
        }
        __syncthreads();
    }

    if (bz < 2) {
        unsigned short* C = (bz == 0) ? qo : ko;
#pragma unroll
        for (int i = 0; i < 4; ++i)
#pragma unroll
            for (int j = 0; j < 4; ++j)
#pragma unroll
                for (int r = 0; r < 4; ++r) {
                    int row = m0 + wave * 64 + i * 16 + lk * 4 + r;
                    int col = n0 + j * 16 + lr;
                    C[(size_t)row * N + col] = f2bf(acc[i][j][r] + bias[col]);
                }
    } else {
        // V^T: vt[((b*16+h)*64 + d)*1024 + n]
#pragma unroll
        for (int i = 0; i < 4; ++i)
#pragma unroll
            for (int j = 0; j < 4; ++j) {
                int row = m0 + wave * 64 + i * 16 + lk * 4;  // base of 4 consecutive n
                int col = n0 + j * 16 + lr;
                int b = row >> 10, n = row & 1023;
                float bb = bias[col];
                ushort4 o4;
                o4.x = f2bf(acc[i][j][0] + bb);
                o4.y = f2bf(acc[i][j][1] + bb);
                o4.z = f2bf(acc[i][j][2] + bb);
                o4.w = f2bf(acc[i][j][3] + bb);
                *(ushort4*)&vt[((size_t)(b * 16 + (col >> 6)) * 64 + (col & 63)) * 1024 + n] = o4;
            }
    }
}

// ---------------- out-proj GEMM + embedded ent/iters finalize --------------------------
__global__ __launch_bounds__(256) void gemm_out(
    const unsigned short* __restrict__ Ab, const unsigned short* __restrict__ Btb,
    const float* __restrict__ bias, float* __restrict__ C,
    const float* __restrict__ ent_part, float* __restrict__ out_ent,
    float* __restrict__ out_iters) {
    const int N = 1024, K = 1024;
    int flat = blockIdx.x + 16 * blockIdx.y;              // 256 blocks
    int vid = (flat & 7) * 32 + (flat >> 3);
    int bx = vid & 15, by = vid >> 4;
    int tid = threadIdx.x;
    int wave = tid >> 6, lane = tid & 63;

    // finalize (runs in block flat==0, wave 0, overlapped with this block's GEMM)
    if (flat == 0 && wave == 0) {
        float s = 0.f;
        if (lane < 32) {
            for (int i = 0; i < 16; ++i) s += ent_part[lane * 16 + i];
            s *= (1.0f / 1024.0f);
            out_ent[lane] = s;
        }
        float m = s;
        m += __shfl_xor(m, 1, 64); m += __shfl_xor(m, 2, 64);
        m += __shfl_xor(m, 4, 64); m += __shfl_xor(m, 8, 64);
        float m1 = __shfl(m, 16, 64);   // batch-1 head-sum (lanes 16-31)
        if (lane == 0) {
            float e0 = m * (1.f / 16.f), e1 = m1 * (1.f / 16.f);
            out_iters[0] = (e0 < 3.0f && e1 < 3.0f) ? 1.0f : 4.0f;
        }
    }

    __shared__ unsigned short As[2][128 * 64];
    __shared__ unsigned short Bs[2][64 * 64];
    int lr = lane & 15, lk = lane >> 4;
    int m0 = bx * 128, n0 = by * 64;
    int wr = wave >> 1, wc = wave & 1;

    f32x4 acc[4][2] = {};

    auto stage = [&](int p, int kk) {
#pragma unroll
        for (int i = 0; i < 4; ++i) {
            int c = tid + 256 * i;
            int r = c >> 3, s = c & 7;
            gload_lds16(Ab + (size_t)(m0 + r) * K + kk + (s ^ (r & 7)) * 8, &As[p][c * 8]);
        }
#pragma unroll
        for (int i = 0; i < 2; ++i) {
            int c = tid + 256 * i;
            int r = c >> 3, s = c & 7;
            gload_lds16(Btb + (size_t)(n0 + r) * K + kk + (s ^ (r & 7)) * 8, &Bs[p][c * 8]);
        }
    };

    stage(0, 0);
    asm volatile("s_waitcnt vmcnt(0)" ::: "memory");
    __syncthreads();

    for (int t = 0; t < 16; ++t) {
        int p = t & 1;
        if (t < 15) stage(p ^ 1, (t + 1) * 64);
#pragma unroll
        for (int ks = 0; ks < 2; ++ks) {
            ushort8 af[4], bfr[2];
#pragma unroll
            for (int f = 0; f < 4; ++f) {
                int row = wr * 64 + f * 16 + lr;
                int cc = ks * 4 + lk;
                af[f] = *(const ushort8*)&As[p][row * 64 + ((cc ^ (row & 7)) * 8)];
            }
#pragma unroll
            for (int f = 0; f < 2; ++f) {
                int row = wc * 32 + f * 16 + lr;
                int cc = ks * 4 + lk;
                bfr[f] = *(const ushort8*)&Bs[p][row * 64 + ((cc ^ (row & 7)) * 8)];
            }
#pragma unroll
            for (int i = 0; i < 4; ++i)
#pragma unroll
                for (int j = 0; j < 2; ++j)
                    acc[i][j] = mfma16(af[i], bfr[j], acc[i][j]);
        }
        __syncthreads();
    }

#pragma unroll
    for (int i = 0; i < 4; ++i)
#pragma unroll
        for (int j = 0; j < 2; ++j)
#pragma unroll
            for (int r = 0; r < 4; ++r) {
                int row = m0 + wr * 64 + i * 16 + lk * 4 + r;
                int col = n0 + wc * 32 + j * 16 + lr;
                C[(size_t)row * N + col] = acc[i][j][r] + bias[col];
            }
}

// ---------------- fused flash attention + entropy ----------------
// QBLK=64, 2 blocks/CU; ZERO-SHUFFLE PV (P in registers, V^T pi-permuted columns);
// swapped QK^T, exp2 fixed-shift softmax, KVBLK=128, 1-tile-ahead reg prefetch.
__global__ __launch_bounds__(256) void attn_kernel(
    const unsigned short* __restrict__ qb, const unsigned short* __restrict__ kb,
    const unsigned short* __restrict__ vtb, const float* __restrict__ res_bias,
    unsigned short* __restrict__ attn_out, float* __restrict__ ent_part) {
    const int S = 1024, D = 1024;
    const float LOG2E = 1.4426950408889634f;
    const float LN2 = 0.6931471805599453f;
    int flat = blockIdx.x + 16 * blockIdx.y;              // 512 blocks
    int vid = (flat & 7) * 64 + (flat >> 3);
    int qt = vid & 15;
    int bh = vid >> 4;
    int b = bh >> 4, h = bh & 15;
    int tid = threadIdx.x;
    int wave = tid >> 6, lane = tid & 63;
    int lr = lane & 15, lk = lane >> 4;

    __shared__ unsigned short Ks[128 * 64];    // [n][d] swizzled, 16KB
    __shared__ unsigned short Vts[64 * 128];   // [d][pi(n)] swizzled, 16KB
    __shared__ float wpart[4];

    const float rbl = res_bias[h] * LOG2E;
    const float c1 = 0.125f * LOG2E;
    const unsigned short* qg = qb + (size_t)(b * S + qt * 64) * D + h * 64;
    const unsigned short* kg = kb + (size_t)(b * S) * D + h * 64;
    const unsigned short* vtg = vtb + (size_t)bh * 64 * 1024;

    // Q fragments: loop-invariant, wave-private rows -> registers, straight from global
    ushort8 qf[2];
#pragma unroll
    for (int ks = 0; ks < 2; ++ks)
        qf[ks] = *(const ushort8*)(qg + (size_t)(wave * 16 + lr) * D + (ks * 4 + lk) * 8);

    // prefetch KV tile 0 into registers
    ushort8 kr[4], vr[4];
#pragma unroll
    for (int i = 0; i < 4; ++i) {
        int c = tid + 256 * i;
        kr[i] = *(const ushort8*)(kg + (size_t)(c >> 3) * D + (c & 7) * 8);
        vr[i] = *(const ushort8*)(vtg + (size_t)(c >> 4) * 1024 + (c & 15) * 8);
    }

    f32x4 o[4] = {};
    float l_ = 0.f, ps_ = 0.f;   // per-lane row stats (log2-domain ps), row q = wave*16+lr

    for (int kt = 0; kt < 8; ++kt) {
        __syncthreads();
        // write prefetched tile to LDS (K swizzled; V permuted pi + swizzled)
#pragma unroll
        for (int i = 0; i < 4; ++i) {
            int c = tid + 256 * i;
            int r1 = c >> 3, d1 = c & 7;
            *(ushort8*)&Ks[r1 * 64 + ((d1 ^ (r1 & 7)) * 8)] = kr[i];
            int r2 = c >> 4, d2 = c & 15;   // d-row, 8-n chunk (n = 8*d2..8*d2+7)
            int b0 = 32 * (d2 >> 2) + 16 * (d2 & 1) + 4 * ((d2 >> 1) & 1);
            int b1 = b0 + 8;
            ushort4 lo, hi;
            lo.x = vr[i][0]; lo.y = vr[i][1]; lo.z = vr[i][2]; lo.w = vr[i][3];
            hi.x = vr[i][4]; hi.y = vr[i][5]; hi.z = vr[i][6]; hi.w = vr[i][7];
            *(ushort4*)&Vts[r2 * 128 + (((b0 >> 3) ^ (r2 & 7)) * 8) + (b0 & 7)] = lo;
            *(ushort4*)&Vts[r2 * 128 + (((b1 >> 3) ^ (r2 & 7)) * 8) + (b1 & 7)] = hi;
        }
        __syncthreads();

        // issue next tile's loads (in flight under compute)
        if (kt < 7) {
#pragma unroll
            for (int i = 0; i < 4; ++i) {
                int c = tid + 256 * i;
                kr[i] = *(const ushort8*)(kg + (size_t)((kt + 1) * 128 + (c >> 3)) * D + (c & 7) * 8);
                vr[i] = *(const ushort8*)(vtg + (size_t)(c >> 4) * 1024 + (kt + 1) * 128 + (c & 15) * 8);
            }
        }

        // S^T = K Q^T: lane holds q = wave*16+lr, P[q][n=16*fj+4*lk+r] in sf[fj][r]
        f32x4 sf[8] = {};
        __builtin_amdgcn_s_setprio(1);
#pragma unroll
        for (int ks = 0; ks < 2; ++ks) {
#pragma unroll
            for (int fj = 0; fj < 8; ++fj) {
                ushort8 kf = *(const ushort8*)&Ks[(fj * 16 + lr) * 64 + (((ks * 4 + lk) ^ (lr & 7)) * 8)];
                sf[fj] = mfma16(kf, qf[ks], sf[fj]);   // A=K, B=Q  -> S^T
            }
        }
        __builtin_amdgcn_s_setprio(0);

        // exp2-domain fixed-shift softmax: t = s*log2e, p = 2^t (exact, |s| < ~3)
        float pl = 0.f, ps = 0.f;
#pragma unroll
        for (int fj = 0; fj < 8; ++fj)
#pragma unroll
            for (int r = 0; r < 4; ++r) {
                float t = sf[fj][r] * c1 + rbl;
                float pe = __builtin_amdgcn_exp2f(t);
                pl += pe; ps = fmaf(pe, t, ps);
                sf[fj][r] = pe;
            }
        // row-sum across the 4 lk replicas
        pl += __shfl_xor(pl, 16, 64); pl += __shfl_xor(pl, 32, 64);
        ps += __shfl_xor(ps, 16, 64); ps += __shfl_xor(ps, 32, 64);
        l_ += pl; ps_ += ps;

        // O += P V: A-frag packed directly from this lane's sf (k-slot (lk,p) holds
        // n = 16*(2ks+(p>>2)) + 4*lk + (p&3), matching Vts' pi layout).
        __builtin_amdgcn_s_setprio(1);
#pragma unroll
        for (int ks = 0; ks < 4; ++ks) {
            ushort8 ap;
            ap[0] = f2bf(sf[2 * ks][0]);     ap[1] = f2bf(sf[2 * ks][1]);
            ap[2] = f2bf(sf[2 * ks][2]);     ap[3] = f2bf(sf[2 * ks][3]);
            ap[4] = f2bf(sf[2 * ks + 1][0]); ap[5] = f2bf(sf[2 * ks + 1][1]);
            ap[6] = f2bf(sf[2 * ks + 1][2]); ap[7] = f2bf(sf[2 * ks + 1][3]);
#pragma unroll
            for (int fd = 0; fd < 4; ++fd) {
                ushort8 bv8 = *(const ushort8*)&Vts[(fd * 16 + lr) * 128 + (((ks * 4 + lk) ^ (lr & 7)) * 8)];
                o[fd] = mfma16(ap, bv8, o[fd]);
            }
        }
        __builtin_amdgcn_s_setprio(0);
    }

    // epilogue: O rows are q = wave*16 + lk*4 + r; stats live at lane lr = row
    float linv = 1.f / l_;
    float ent_row = __logf(l_) - LN2 * ps_ * linv;
    float linv_r[4];
#pragma unroll
    for (int r = 0; r < 4; ++r) linv_r[r] = __shfl(linv, lk * 4 + r, 64);
#pragma unroll
    for (int r = 0; r < 4; ++r) {
        int row = b * S + qt * 64 + wave * 16 + lk * 4 + r;
#pragma unroll
        for (int fd = 0; fd < 4; ++fd) {
            int col = h * 64 + fd * 16 + lr;
            attn_out[(size_t)row * D + col] = f2bf(o[fd][r] * linv_r[r]);
        }
    }
    // entropy: sum rows 0..15 within each 16-lane group (lk replicas identical)
    float es = ent_row;
    es += __shfl_xor(es, 1, 64);
    es += __shfl_xor(es, 2, 64);
    es += __shfl_xor(es, 4, 64);
    es += __shfl_xor(es, 8, 64);
    if (lane == 0) wpart[wave] = es;
    __syncthreads();
    if (tid == 0) ent_part[bh * 16 + qt] = wpart[0] + wpart[1] + wpart[2] + wpart[3];
}

extern "C" void kernel_launch(void* const* d_in, const int* in_sizes, int n_in,
                              void* d_out, int out_size, void* d_ws, size_t ws_size,
                              hipStream_t stream) {
    const float* x  = (const float*)d_in[0];
    const float* wq = (const float*)d_in[1];
    const float* bq = (const float*)d_in[2];
    const float* wk = (const float*)d_in[3];
    const float* bk = (const float*)d_in[4];
    const float* wv = (const float*)d_in[5];
    const float* bv = (const float*)d_in[6];
    const float* wo = (const float*)d_in[7];
    const float* bo = (const float*)d_in[8];
    const float* rbias = (const float*)d_in[9];

    char* ws = (char*)d_ws;
    unsigned short* xb  = (unsigned short*)(ws);                      // 4 MB
    unsigned short* wqb = (unsigned short*)(ws + ((size_t)4 << 20));  // 2 MB
    unsigned short* wkb = (unsigned short*)(ws + ((size_t)6 << 20));
    unsigned short* wvb = (unsigned short*)(ws + ((size_t)8 << 20));
    unsigned short* wob = (unsigned short*)(ws + ((size_t)10 << 20));
    unsigned short* qbf = (unsigned short*)(ws + ((size_t)12 << 20));
    unsigned short* kbf = (unsigned short*)(ws + ((size_t)16 << 20));
    unsigned short* vtb = (unsigned short*)(ws + ((size_t)20 << 20)); // V^T [32][64][1024]
    unsigned short* aob = (unsigned short*)(ws + ((size_t)24 << 20));
    float* ent_part = (float*)(ws + ((size_t)28 << 20));

    float* out = (float*)d_out;
    float* out_ent = out + (size_t)2 * 1024 * 1024;
    float* out_iters = out_ent + 32;

    cvt_all_kernel<<<dim3(3072), dim3(256), 0, stream>>>(x, wq, wk, wv, wo, xb);
    gemm_qkv<<<dim3(16, 16, 3), dim3(128), 0, stream>>>(xb, wqb, wkb, wvb, bq, bk, bv, qbf, kbf, vtb);
    attn_kernel<<<dim3(16, 32), dim3(256), 0, stream>>>(qbf, kbf, vtb, rbias, aob, ent_part);
    gemm_out<<<dim3(16, 16), dim3(256), 0, stream>>>(aob, wob, bo, out, ent_part, out_ent, out_iters);
}

// Round 13
// 64.744 us; speedup vs baseline: 1.1302x; 1.1302x over previous
//
#include <hip/hip_runtime.h>
#include <hip/hip_bf16.h>

typedef __attribute__((ext_vector_type(4))) float f32x4;
typedef __attribute__((ext_vector_type(8))) __bf16 bf16x8;
typedef __attribute__((ext_vector_type(8))) unsigned short ushort8;

__device__ __forceinline__ unsigned short f2bf(float f) {
    return __builtin_bit_cast(unsigned short, (__bf16)f);   // native RNE cvt (gfx950)
}

__device__ __forceinline__ f32x4 mfma16(ushort8 a, ushort8 b, f32x4 c) {
    return __builtin_amdgcn_mfma_f32_16x16x32_bf16(
        __builtin_bit_cast(bf16x8, a), __builtin_bit_cast(bf16x8, b), c, 0, 0, 0);
}

__device__ __forceinline__ void gload_lds16(const unsigned short* g, unsigned short* l) {
    __builtin_amdgcn_global_load_lds(
        (const __attribute__((address_space(1))) unsigned int*)g,
        (__attribute__((address_space(3))) unsigned int*)l, 16, 0, 0);
}

// ---------------- fused f32 -> bf16 convert, 32B/thread: x, wq, wk, wv, wo ----------
__global__ __launch_bounds__(256) void cvt_all_kernel(
    const float* __restrict__ x, const float* __restrict__ wq, const float* __restrict__ wk,
    const float* __restrict__ wv, const float* __restrict__ wo, unsigned short* __restrict__ dst) {
    int i = blockIdx.x * blockDim.x + threadIdx.x;  // float4-PAIR index, total 786432
    const float* src;
    size_t off;
    if (i < 262144) { src = x; off = i; }
    else {
        int j = i - 262144;
        int w = j >> 17;
        off = (size_t)(j & 131071);
        src = (w == 0) ? wq : (w == 1) ? wk : (w == 2) ? wv : wo;
    }
    float4 a = ((const float4*)src)[off * 2];
    float4 b = ((const float4*)src)[off * 2 + 1];
    ushort8 o;
    o[0] = f2bf(a.x); o[1] = f2bf(a.y); o[2] = f2bf(a.z); o[3] = f2bf(a.w);
    o[4] = f2bf(b.x); o[5] = f2bf(b.y); o[6] = f2bf(b.z); o[7] = f2bf(b.w);
    *(ushort8*)&dst[(size_t)i * 8] = o;
}

// ---------------- bt-GEMM qkv: 128x64 tile, BK=64, 2-phase dbuf, both-sides swizzle,
// XCD block swizzle. 48KB LDS -> 3 blocks/CU, 768 blocks = exactly 3/CU balanced. ------
__global__ __launch_bounds__(256) void gemm_qkv(
    const unsigned short* __restrict__ xb,
    const unsigned short* __restrict__ wqb, const unsigned short* __restrict__ wkb,
    const unsigned short* __restrict__ wvb,
    const float* __restrict__ bq, const float* __restrict__ bk, const float* __restrict__ bv,
    unsigned short* __restrict__ qo, unsigned short* __restrict__ ko, unsigned short* __restrict__ vt) {
    const int N = 1024, K = 1024;
    int flat = blockIdx.x + 16 * blockIdx.y + 256 * blockIdx.z;   // 768 blocks
    int vid = (flat & 7) * 96 + (flat >> 3);                      // XCD-contiguous
    int bx = vid & 15, by = (vid >> 4) & 15, bz = vid >> 8;
    const unsigned short* Bt = (bz == 0) ? wqb : (bz == 1) ? wkb : wvb;
    const float* bias = (bz == 0) ? bq : (bz == 1) ? bk : bv;

    __shared__ unsigned short As[2][128 * 64];
    __shared__ unsigned short Bs[2][64 * 64];
    int tid = threadIdx.x;
    int wave = tid >> 6, lane = tid & 63;
    int lr = lane & 15, lk = lane >> 4;
    int m0 = bx * 128, n0 = by * 64;
    int wr = wave >> 1, wc = wave & 1;

    f32x4 acc[4][2] = {};

    auto stage = [&](int p, int kk) {
#pragma unroll
        for (int i = 0; i < 4; ++i) {
            int c = tid + 256 * i;
            int r = c >> 3, s = c & 7;
            gload_lds16(xb + (size_t)(m0 + r) * K + kk + (s ^ (r & 7)) * 8, &As[p][c * 8]);
        }
#pragma unroll
        for (int i = 0; i < 2; ++i) {
            int c = tid + 256 * i;
            int r = c >> 3, s = c & 7;
            gload_lds16(Bt + (size_t)(n0 + r) * K + kk + (s ^ (r & 7)) * 8, &Bs[p][c * 8]);
        }
    };

    stage(0, 0);
    asm volatile("s_waitcnt vmcnt(0)" ::: "memory");
    __syncthreads();

    for (int t = 0; t < 16; ++t) {
        int p = t & 1;
        if (t < 15) stage(p ^ 1, (t + 1) * 64);
#pragma unroll
        for (int ks = 0; ks < 2; ++ks) {
            ushort8 af[4], bfr[2];
#pragma unroll
            for (int f = 0; f < 4; ++f) {
                int row = wr * 64 + f * 16 + lr;
                int cc = ks * 4 + lk;
                af[f] = *(const ushort8*)&As[p][row * 64 + ((cc ^ (row & 7)) * 8)];
            }
#pragma unroll
            for (int f = 0; f < 2; ++f) {
                int row = wc * 32 + f * 16 + lr;
                int cc = ks * 4 + lk;
                bfr[f] = *(const ushort8*)&Bs[p][row * 64 + ((cc ^ (row & 7)) * 8)];
            }
#pragma unroll
            for (int i = 0; i < 4; ++i)
#pragma unroll
                for (int j = 0; j < 2; ++j)
                    acc[i][j] = mfma16(af[i], bfr[j], acc[i][j]);
        }
        __syncthreads();
    }

    if (bz < 2) {
        unsigned short* C = (bz == 0) ? qo : ko;
#pragma unroll
        for (int i = 0; i < 4; ++i)
#pragma unroll
            for (int j = 0; j < 2; ++j)
#pragma unroll
                for (int r = 0; r < 4; ++r) {
                    int row = m0 + wr * 64 + i * 16 + lk * 4 + r;
                    int col = n0 + wc * 32 + j * 16 + lr;
                    C[(size_t)row * N + col] = f2bf(acc[i][j][r] + bias[col]);
                }
    } else {
        // V^T: vt[((b*16+h)*64 + d)*1024 + n]
#pragma unroll
        for (int i = 0; i < 4; ++i)
#pragma unroll
            for (int j = 0; j < 2; ++j) {
                int row = m0 + wr * 64 + i * 16 + lk * 4;  // base of 4 consecutive n
                int col = n0 + wc * 32 + j * 16 + lr;
                int b = row >> 10, n = row & 1023;
                float bb = bias[col];
                ushort4 o4;
                o4.x = f2bf(acc[i][j][0] + bb);
                o4.y = f2bf(acc[i][j][1] + bb);
                o4.z = f2bf(acc[i][j][2] + bb);
                o4.w = f2bf(acc[i][j][3] + bb);
                *(ushort4*)&vt[((size_t)(b * 16 + (col >> 6)) * 64 + (col & 63)) * 1024 + n] = o4;
            }
    }
}

// ---------------- out-proj GEMM + embedded ent/iters finalize --------------------------
__global__ __launch_bounds__(256) void gemm_out(
    const unsigned short* __restrict__ Ab, const unsigned short* __restrict__ Btb,
    const float* __restrict__ bias, float* __restrict__ C,
    const float* __restrict__ ent_part, float* __restrict__ out_ent,
    float* __restrict__ out_iters) {
    const int N = 1024, K = 1024;
    int flat = blockIdx.x + 16 * blockIdx.y;              // 256 blocks
    int vid = (flat & 7) * 32 + (flat >> 3);
    int bx = vid & 15, by = vid >> 4;
    int tid = threadIdx.x;
    int wave = tid >> 6, lane = tid & 63;

    // finalize (runs in block flat==0, wave 0, overlapped with this block's GEMM)
    if (flat == 0 && wave == 0) {
        float s = 0.f;
        if (lane < 32) {
            for (int i = 0; i < 16; ++i) s += ent_part[lane * 16 + i];
            s *= (1.0f / 1024.0f);
            out_ent[lane] = s;
        }
        float m = s;
        m += __shfl_xor(m, 1, 64); m += __shfl_xor(m, 2, 64);
        m += __shfl_xor(m, 4, 64); m += __shfl_xor(m, 8, 64);
        float m1 = __shfl(m, 16, 64);   // batch-1 head-sum (lanes 16-31)
        if (lane == 0) {
            float e0 = m * (1.f / 16.f), e1 = m1 * (1.f / 16.f);
            out_iters[0] = (e0 < 3.0f && e1 < 3.0f) ? 1.0f : 4.0f;
        }
    }

    __shared__ unsigned short As[2][128 * 64];
    __shared__ unsigned short Bs[2][64 * 64];
    int lr = lane & 15, lk = lane >> 4;
    int m0 = bx * 128, n0 = by * 64;
    int wr = wave >> 1, wc = wave & 1;

    f32x4 acc[4][2] = {};

    auto stage = [&](int p, int kk) {
#pragma unroll
        for (int i = 0; i < 4; ++i) {
            int c = tid + 256 * i;
            int r = c >> 3, s = c & 7;
            gload_lds16(Ab + (size_t)(m0 + r) * K + kk + (s ^ (r & 7)) * 8, &As[p][c * 8]);
        }
#pragma unroll
        for (int i = 0; i < 2; ++i) {
            int c = tid + 256 * i;
            int r = c >> 3, s = c & 7;
            gload_lds16(Btb + (size_t)(n0 + r) * K + kk + (s ^ (r & 7)) * 8, &Bs[p][c * 8]);
        }
    };

    stage(0, 0);
    asm volatile("s_waitcnt vmcnt(0)" ::: "memory");
    __syncthreads();

    for (int t = 0; t < 16; ++t) {
        int p = t & 1;
        if (t < 15) stage(p ^ 1, (t + 1) * 64);
#pragma unroll
        for (int ks = 0; ks < 2; ++ks) {
            ushort8 af[4], bfr[2];
#pragma unroll
            for (int f = 0; f < 4; ++f) {
                int row = wr * 64 + f * 16 + lr;
                int cc = ks * 4 + lk;
                af[f] = *(const ushort8*)&As[p][row * 64 + ((cc ^ (row & 7)) * 8)];
            }
#pragma unroll
            for (int f = 0; f < 2; ++f) {
                int row = wc * 32 + f * 16 + lr;
                int cc = ks * 4 + lk;
                bfr[f] = *(const ushort8*)&Bs[p][row * 64 + ((cc ^ (row & 7)) * 8)];
            }
#pragma unroll
            for (int i = 0; i < 4; ++i)
#pragma unroll
                for (int j = 0; j < 2; ++j)
                    acc[i][j] = mfma16(af[i], bfr[j], acc[i][j]);
        }
        __syncthreads();
    }

#pragma unroll
    for (int i = 0; i < 4; ++i)
#pragma unroll
        for (int j = 0; j < 2; ++j)
#pragma unroll
            for (int r = 0; r < 4; ++r) {
                int row = m0 + wr * 64 + i * 16 + lk * 4 + r;
                int col = n0 + wc * 32 + j * 16 + lr;
                C[(size_t)row * N + col] = acc[i][j][r] + bias[col];
            }
}

// ---------------- fused flash attention + entropy ----------------
// QBLK=64, 2 blocks/CU; ZERO-SHUFFLE PV (P in registers, V^T pi-permuted columns);
// swapped QK^T, exp2 fixed-shift softmax, KVBLK=128, 1-tile-ahead reg prefetch.
__global__ __launch_bounds__(256) void attn_kernel(
    const unsigned short* __restrict__ qb, const unsigned short* __restrict__ kb,
    const unsigned short* __restrict__ vtb, const float* __restrict__ res_bias,
    unsigned short* __restrict__ attn_out, float* __restrict__ ent_part) {
    const int S = 1024, D = 1024;
    const float LOG2E = 1.4426950408889634f;
    const float LN2 = 0.6931471805599453f;
    int flat = blockIdx.x + 16 * blockIdx.y;              // 512 blocks
    int vid = (flat & 7) * 64 + (flat >> 3);
    int qt = vid & 15;
    int bh = vid >> 4;
    int b = bh >> 4, h = bh & 15;
    int tid = threadIdx.x;
    int wave = tid >> 6, lane = tid & 63;
    int lr = lane & 15, lk = lane >> 4;

    __shared__ unsigned short Ks[128 * 64];    // [n][d] swizzled, 16KB
    __shared__ unsigned short Vts[64 * 128];   // [d][pi(n)] swizzled, 16KB
    __shared__ float wpart[4];

    const float rbl = res_bias[h] * LOG2E;
    const float c1 = 0.125f * LOG2E;
    const unsigned short* qg = qb + (size_t)(b * S + qt * 64) * D + h * 64;
    const unsigned short* kg = kb + (size_t)(b * S) * D + h * 64;
    const unsigned short* vtg = vtb + (size_t)bh * 64 * 1024;

    // Q fragments: loop-invariant, wave-private rows -> registers, straight from global
    ushort8 qf[2];
#pragma unroll
    for (int ks = 0; ks < 2; ++ks)
        qf[ks] = *(const ushort8*)(qg + (size_t)(wave * 16 + lr) * D + (ks * 4 + lk) * 8);

    // prefetch KV tile 0 into registers
    ushort8 kr[4], vr[4];
#pragma unroll
    for (int i = 0; i < 4; ++i) {
        int c = tid + 256 * i;
        kr[i] = *(const ushort8*)(kg + (size_t)(c >> 3) * D + (c & 7) * 8);
        vr[i] = *(const ushort8*)(vtg + (size_t)(c >> 4) * 1024 + (c & 15) * 8);
    }

    f32x4 o[4] = {};
    float l_ = 0.f, ps_ = 0.f;   // per-lane row stats (log2-domain ps), row q = wave*16+lr

    for (int kt = 0; kt < 8; ++kt) {
        __syncthreads();
        // write prefetched tile to LDS (K swizzled; V permuted pi + swizzled)
#pragma unroll
        for (int i = 0; i < 4; ++i) {
            int c = tid + 256 * i;
            int r1 = c >> 3, d1 = c & 7;
            *(ushort8*)&Ks[r1 * 64 + ((d1 ^ (r1 & 7)) * 8)] = kr[i];
            int r2 = c >> 4, d2 = c & 15;   // d-row, 8-n chunk (n = 8*d2..8*d2+7)
            int b0 = 32 * (d2 >> 2) + 16 * (d2 & 1) + 4 * ((d2 >> 1) & 1);
            int b1 = b0 + 8;
            ushort4 lo, hi;
            lo.x = vr[i][0]; lo.y = vr[i][1]; lo.z = vr[i][2]; lo.w = vr[i][3];
            hi.x = vr[i][4]; hi.y = vr[i][5]; hi.z = vr[i][6]; hi.w = vr[i][7];
            *(ushort4*)&Vts[r2 * 128 + (((b0 >> 3) ^ (r2 & 7)) * 8) + (b0 & 7)] = lo;
            *(ushort4*)&Vts[r2 * 128 + (((b1 >> 3) ^ (r2 & 7)) * 8) + (b1 & 7)] = hi;
        }
        __syncthreads();

        // issue next tile's loads (in flight under compute)
        if (kt < 7) {
#pragma unroll
            for (int i = 0; i < 4; ++i) {
                int c = tid + 256 * i;
                kr[i] = *(const ushort8*)(kg + (size_t)((kt + 1) * 128 + (c >> 3)) * D + (c & 7) * 8);
                vr[i] = *(const ushort8*)(vtg + (size_t)(c >> 4) * 1024 + (kt + 1) * 128 + (c & 15) * 8);
            }
        }

        // S^T = K Q^T: lane holds q = wave*16+lr, P[q][n=16*fj+4*lk+r] in sf[fj][r]
        f32x4 sf[8] = {};
        __builtin_amdgcn_s_setprio(1);
#pragma unroll
        for (int ks = 0; ks < 2; ++ks) {
#pragma unroll
            for (int fj = 0; fj < 8; ++fj) {
                ushort8 kf = *(const ushort8*)&Ks[(fj * 16 + lr) * 64 + (((ks * 4 + lk) ^ (lr & 7)) * 8)];
                sf[fj] = mfma16(kf, qf[ks], sf[fj]);   // A=K, B=Q  -> S^T
            }
        }
        __builtin_amdgcn_s_setprio(0);

        // exp2-domain fixed-shift softmax: t = s*log2e, p = 2^t (exact, |s| < ~3)
        float pl = 0.f, ps = 0.f;
#pragma unroll
        for (int fj = 0; fj < 8; ++fj)
#pragma unroll
            for (int r = 0; r < 4; ++r) {
                float t = sf[fj][r] * c1 + rbl;
                float pe = __builtin_amdgcn_exp2f(t);
                pl += pe; ps = fmaf(pe, t, ps);
                sf[fj][r] = pe;
            }
        // row-sum across the 4 lk replicas
        pl += __shfl_xor(pl, 16, 64); pl += __shfl_xor(pl, 32, 64);
        ps += __shfl_xor(ps, 16, 64); ps += __shfl_xor(ps, 32, 64);
        l_ += pl; ps_ += ps;

        // O += P V: A-frag packed directly from this lane's sf (k-slot (lk,p) holds
        // n = 16*(2ks+(p>>2)) + 4*lk + (p&3), matching Vts' pi layout).
        __builtin_amdgcn_s_setprio(1);
#pragma unroll
        for (int ks = 0; ks < 4; ++ks) {
            ushort8 ap;
            ap[0] = f2bf(sf[2 * ks][0]);     ap[1] = f2bf(sf[2 * ks][1]);
            ap[2] = f2bf(sf[2 * ks][2]);     ap[3] = f2bf(sf[2 * ks][3]);
            ap[4] = f2bf(sf[2 * ks + 1][0]); ap[5] = f2bf(sf[2 * ks + 1][1]);
            ap[6] = f2bf(sf[2 * ks + 1][2]); ap[7] = f2bf(sf[2 * ks + 1][3]);
#pragma unroll
            for (int fd = 0; fd < 4; ++fd) {
                ushort8 bv8 = *(const ushort8*)&Vts[(fd * 16 + lr) * 128 + (((ks * 4 + lk) ^ (lr & 7)) * 8)];
                o[fd] = mfma16(ap, bv8, o[fd]);
            }
        }
        __builtin_amdgcn_s_setprio(0);
    }

    // epilogue: O rows are q = wave*16 + lk*4 + r; stats live at lane lr = row
    float linv = 1.f / l_;
    float ent_row = __logf(l_) - LN2 * ps_ * linv;
    float linv_r[4];
#pragma unroll
    for (int r = 0; r < 4; ++r) linv_r[r] = __shfl(linv, lk * 4 + r, 64);
#pragma unroll
    for (int r = 0; r < 4; ++r) {
        int row = b * S + qt * 64 + wave * 16 + lk * 4 + r;
#pragma unroll
        for (int fd = 0; fd < 4; ++fd) {
            int col = h * 64 + fd * 16 + lr;
            attn_out[(size_t)row * D + col] = f2bf(o[fd][r] * linv_r[r]);
        }
    }
    // entropy: sum rows 0..15 within each 16-lane group (lk replicas identical)
    float es = ent_row;
    es += __shfl_xor(es, 1, 64);
    es += __shfl_xor(es, 2, 64);
    es += __shfl_xor(es, 4, 64);
    es += __shfl_xor(es, 8, 64);
    if (lane == 0) wpart[wave] = es;
    __syncthreads();
    if (tid == 0) ent_part[bh * 16 + qt] = wpart[0] + wpart[1] + wpart[2] + wpart[3];
}

extern "C" void kernel_launch(void* const* d_in, const int* in_sizes, int n_in,
                              void* d_out, int out_size, void* d_ws, size_t ws_size,
                              hipStream_t stream) {
    const float* x  = (const float*)d_in[0];
    const float* wq = (const float*)d_in[1];
    const float* bq = (const float*)d_in[2];
    const float* wk = (const float*)d_in[3];
    const float* bk = (const float*)d_in[4];
    const float* wv = (const float*)d_in[5];
    const float* bv = (const float*)d_in[6];
    const float* wo = (const float*)d_in[7];
    const float* bo = (const float*)d_in[8];
    const float* rbias = (const float*)d_in[9];

    char* ws = (char*)d_ws;
    unsigned short* xb  = (unsigned short*)(ws);                      // 4 MB
    unsigned short* wqb = (unsigned short*)(ws + ((size_t)4 << 20));  // 2 MB
    unsigned short* wkb = (unsigned short*)(ws + ((size_t)6 << 20));
    unsigned short* wvb = (unsigned short*)(ws + ((size_t)8 << 20));
    unsigned short* wob = (unsigned short*)(ws + ((size_t)10 << 20));
    unsigned short* qbf = (unsigned short*)(ws + ((size_t)12 << 20));
    unsigned short* kbf = (unsigned short*)(ws + ((size_t)16 << 20));
    unsigned short* vtb = (unsigned short*)(ws + ((size_t)20 << 20)); // V^T [32][64][1024]
    unsigned short* aob = (unsigned short*)(ws + ((size_t)24 << 20));
    float* ent_part = (float*)(ws + ((size_t)28 << 20));

    float* out = (float*)d_out;
    float* out_ent = out + (size_t)2 * 1024 * 1024;
    float* out_iters = out_ent + 32;

    cvt_all_kernel<<<dim3(3072), dim3(256), 0, stream>>>(x, wq, wk, wv, wo, xb);
    gemm_qkv<<<dim3(16, 16, 3), dim3(256), 0, stream>>>(xb, wqb, wkb, wvb, bq, bk, bv, qbf, kbf, vtb);
    attn_kernel<<<dim3(16, 32), dim3(256), 0, stream>>>(qbf, kbf, vtb, rbias, aob, ent_part);
    gemm_out<<<dim3(16, 16), dim3(256), 0, stream>>>(aob, wob, bo, out, ent_part, out_ent, out_iters);
}

// Round 14
// 63.767 us; speedup vs baseline: 1.1475x; 1.0153x over previous
//
#include <hip/hip_runtime.h>
#include <hip/hip_bf16.h>

typedef __attribute__((ext_vector_type(4))) float f32x4;
typedef __attribute__((ext_vector_type(8))) __bf16 bf16x8;
typedef __attribute__((ext_vector_type(8))) unsigned short ushort8;

__device__ __forceinline__ unsigned short f2bf(float f) {
    return __builtin_bit_cast(unsigned short, (__bf16)f);   // native RNE cvt (gfx950)
}

__device__ __forceinline__ f32x4 mfma16(ushort8 a, ushort8 b, f32x4 c) {
    return __builtin_amdgcn_mfma_f32_16x16x32_bf16(
        __builtin_bit_cast(bf16x8, a), __builtin_bit_cast(bf16x8, b), c, 0, 0, 0);
}

__device__ __forceinline__ void gload_lds16(const unsigned short* g, unsigned short* l) {
    __builtin_amdgcn_global_load_lds(
        (const __attribute__((address_space(1))) unsigned int*)g,
        (__attribute__((address_space(3))) unsigned int*)l, 16, 0, 0);
}

// ---------------- fused f32 -> bf16 convert, 32B/thread: x, wq, wk, wv, wo ----------
__global__ __launch_bounds__(256) void cvt_all_kernel(
    const float* __restrict__ x, const float* __restrict__ wq, const float* __restrict__ wk,
    const float* __restrict__ wv, const float* __restrict__ wo, unsigned short* __restrict__ dst) {
    int i = blockIdx.x * blockDim.x + threadIdx.x;  // float4-PAIR index, total 786432
    const float* src;
    size_t off;
    if (i < 262144) { src = x; off = i; }
    else {
        int j = i - 262144;
        int w = j >> 17;
        off = (size_t)(j & 131071);
        src = (w == 0) ? wq : (w == 1) ? wk : (w == 2) ? wv : wo;
    }
    float4 a = ((const float4*)src)[off * 2];
    float4 b = ((const float4*)src)[off * 2 + 1];
    ushort8 o;
    o[0] = f2bf(a.x); o[1] = f2bf(a.y); o[2] = f2bf(a.z); o[3] = f2bf(a.w);
    o[4] = f2bf(b.x); o[5] = f2bf(b.y); o[6] = f2bf(b.z); o[7] = f2bf(b.w);
    *(ushort8*)&dst[(size_t)i * 8] = o;
}

// ---------------- bt-GEMM qkv: 128x64 tile, BK=64, 2-phase dbuf, both-sides swizzle,
// XCD block swizzle. 48KB LDS -> 3 blocks/CU, 768 blocks = exactly 3/CU balanced. ------
__global__ __launch_bounds__(256) void gemm_qkv(
    const unsigned short* __restrict__ xb,
    const unsigned short* __restrict__ wqb, const unsigned short* __restrict__ wkb,
    const unsigned short* __restrict__ wvb,
    const float* __restrict__ bq, const float* __restrict__ bk, const float* __restrict__ bv,
    unsigned short* __restrict__ qo, unsigned short* __restrict__ ko, unsigned short* __restrict__ vt) {
    const int N = 1024, K = 1024;
    int flat = blockIdx.x + 16 * blockIdx.y + 256 * blockIdx.z;   // 768 blocks
    int vid = (flat & 7) * 96 + (flat >> 3);                      // XCD-contiguous
    int bx = vid & 15, by = (vid >> 4) & 15, bz = vid >> 8;
    const unsigned short* Bt = (bz == 0) ? wqb : (bz == 1) ? wkb : wvb;
    const float* bias = (bz == 0) ? bq : (bz == 1) ? bk : bv;

    __shared__ unsigned short As[2][128 * 64];
    __shared__ unsigned short Bs[2][64 * 64];
    int tid = threadIdx.x;
    int wave = tid >> 6, lane = tid & 63;
    int lr = lane & 15, lk = lane >> 4;
    int m0 = bx * 128, n0 = by * 64;
    int wr = wave >> 1, wc = wave & 1;

    f32x4 acc[4][2] = {};

    auto stage = [&](int p, int kk) {
#pragma unroll
        for (int i = 0; i < 4; ++i) {
            int c = tid + 256 * i;
            int r = c >> 3, s = c & 7;
            gload_lds16(xb + (size_t)(m0 + r) * K + kk + (s ^ (r & 7)) * 8, &As[p][c * 8]);
        }
#pragma unroll
        for (int i = 0; i < 2; ++i) {
            int c = tid + 256 * i;
            int r = c >> 3, s = c & 7;
            gload_lds16(Bt + (size_t)(n0 + r) * K + kk + (s ^ (r & 7)) * 8, &Bs[p][c * 8]);
        }
    };

    stage(0, 0);
    asm volatile("s_waitcnt vmcnt(0)" ::: "memory");
    __syncthreads();

    for (int t = 0; t < 16; ++t) {
        int p = t & 1;
        if (t < 15) stage(p ^ 1, (t + 1) * 64);
#pragma unroll
        for (int ks = 0; ks < 2; ++ks) {
            ushort8 af[4], bfr[2];
#pragma unroll
            for (int f = 0; f < 4; ++f) {
                int row = wr * 64 + f * 16 + lr;
                int cc = ks * 4 + lk;
                af[f] = *(const ushort8*)&As[p][row * 64 + ((cc ^ (row & 7)) * 8)];
            }
#pragma unroll
            for (int f = 0; f < 2; ++f) {
                int row = wc * 32 + f * 16 + lr;
                int cc = ks * 4 + lk;
                bfr[f] = *(const ushort8*)&Bs[p][row * 64 + ((cc ^ (row & 7)) * 8)];
            }
#pragma unroll
            for (int i = 0; i < 4; ++i)
#pragma unroll
                for (int j = 0; j < 2; ++j)
                    acc[i][j] = mfma16(af[i], bfr[j], acc[i][j]);
        }
        __syncthreads();
    }

    if (bz < 2) {
        unsigned short* C = (bz == 0) ? qo : ko;
#pragma unroll
        for (int i = 0; i < 4; ++i)
#pragma unroll
            for (int j = 0; j < 2; ++j)
#pragma unroll
                for (int r = 0; r < 4; ++r) {
                    int row = m0 + wr * 64 + i * 16 + lk * 4 + r;
                    int col = n0 + wc * 32 + j * 16 + lr;
                    C[(size_t)row * N + col] = f2bf(acc[i][j][r] + bias[col]);
                }
    } else {
        // V^T: vt[((b*16+h)*64 + d)*1024 + n]
#pragma unroll
        for (int i = 0; i < 4; ++i)
#pragma unroll
            for (int j = 0; j < 2; ++j) {
                int row = m0 + wr * 64 + i * 16 + lk * 4;  // base of 4 consecutive n
                int col = n0 + wc * 32 + j * 16 + lr;
                int b = row >> 10, n = row & 1023;
                float bb = bias[col];
                ushort4 o4;
                o4.x = f2bf(acc[i][j][0] + bb);
                o4.y = f2bf(acc[i][j][1] + bb);
                o4.z = f2bf(acc[i][j][2] + bb);
                o4.w = f2bf(acc[i][j][3] + bb);
                *(ushort4*)&vt[((size_t)(b * 16 + (col >> 6)) * 64 + (col & 63)) * 1024 + n] = o4;
            }
    }
}

// ---------------- out-proj GEMM (64x64 tile, 512 blocks = 2/CU) + ent/iters finalize ---
__global__ __launch_bounds__(256) void gemm_out(
    const unsigned short* __restrict__ Ab, const unsigned short* __restrict__ Btb,
    const float* __restrict__ bias, float* __restrict__ C,
    const float* __restrict__ ent_part, float* __restrict__ out_ent,
    float* __restrict__ out_iters) {
    const int N = 1024, K = 1024;
    int flat = blockIdx.x + 32 * blockIdx.y;              // 512 blocks
    int vid = (flat & 7) * 64 + (flat >> 3);              // XCD-contiguous
    int bx = vid & 31, by = vid >> 5;
    int tid = threadIdx.x;
    int wave = tid >> 6, lane = tid & 63;

    // finalize (runs in block flat==0, wave 0, overlapped with this block's GEMM)
    if (flat == 0 && wave == 0) {
        float s = 0.f;
        if (lane < 32) {
            for (int i = 0; i < 16; ++i) s += ent_part[lane * 16 + i];
            s *= (1.0f / 1024.0f);
            out_ent[lane] = s;
        }
        float m = s;
        m += __shfl_xor(m, 1, 64); m += __shfl_xor(m, 2, 64);
        m += __shfl_xor(m, 4, 64); m += __shfl_xor(m, 8, 64);
        float m1 = __shfl(m, 16, 64);   // batch-1 head-sum (lanes 16-31)
        if (lane == 0) {
            float e0 = m * (1.f / 16.f), e1 = m1 * (1.f / 16.f);
            out_iters[0] = (e0 < 3.0f && e1 < 3.0f) ? 1.0f : 4.0f;
        }
    }

    __shared__ unsigned short As[2][64 * 64];
    __shared__ unsigned short Bs[2][64 * 64];
    int lr = lane & 15, lk = lane >> 4;
    int m0 = bx * 64, n0 = by * 64;
    int wr = wave >> 1, wc = wave & 1;

    f32x4 acc[2][2] = {};

    auto stage = [&](int p, int kk) {
#pragma unroll
        for (int i = 0; i < 2; ++i) {
            int c = tid + 256 * i;
            int r = c >> 3, s = c & 7;
            gload_lds16(Ab + (size_t)(m0 + r) * K + kk + (s ^ (r & 7)) * 8, &As[p][c * 8]);
        }
#pragma unroll
        for (int i = 0; i < 2; ++i) {
            int c = tid + 256 * i;
            int r = c >> 3, s = c & 7;
            gload_lds16(Btb + (size_t)(n0 + r) * K + kk + (s ^ (r & 7)) * 8, &Bs[p][c * 8]);
        }
    };

    stage(0, 0);
    asm volatile("s_waitcnt vmcnt(0)" ::: "memory");
    __syncthreads();

    for (int t = 0; t < 16; ++t) {
        int p = t & 1;
        if (t < 15) stage(p ^ 1, (t + 1) * 64);
#pragma unroll
        for (int ks = 0; ks < 2; ++ks) {
            ushort8 af[2], bfr[2];
#pragma unroll
            for (int f = 0; f < 2; ++f) {
                int row = wr * 32 + f * 16 + lr;
                int cc = ks * 4 + lk;
                af[f] = *(const ushort8*)&As[p][row * 64 + ((cc ^ (row & 7)) * 8)];
            }
#pragma unroll
            for (int f = 0; f < 2; ++f) {
                int row = wc * 32 + f * 16 + lr;
                int cc = ks * 4 + lk;
                bfr[f] = *(const ushort8*)&Bs[p][row * 64 + ((cc ^ (row & 7)) * 8)];
            }
#pragma unroll
            for (int i = 0; i < 2; ++i)
#pragma unroll
                for (int j = 0; j < 2; ++j)
                    acc[i][j] = mfma16(af[i], bfr[j], acc[i][j]);
        }
        __syncthreads();
    }

#pragma unroll
    for (int i = 0; i < 2; ++i)
#pragma unroll
        for (int j = 0; j < 2; ++j)
#pragma unroll
            for (int r = 0; r < 4; ++r) {
                int row = m0 + wr * 32 + i * 16 + lk * 4 + r;
                int col = n0 + wc * 32 + j * 16 + lr;
                C[(size_t)row * N + col] = acc[i][j][r] + bias[col];
            }
}

// ---------------- fused flash attention + entropy ----------------
// QBLK=64, 2 blocks/CU; ZERO-SHUFFLE PV (P in registers, V^T pi-permuted columns);
// swapped QK^T, exp2 fixed-shift softmax, KVBLK=128, 1-tile-ahead reg prefetch.
__global__ __launch_bounds__(256) void attn_kernel(
    const unsigned short* __restrict__ qb, const unsigned short* __restrict__ kb,
    const unsigned short* __restrict__ vtb, const float* __restrict__ res_bias,
    unsigned short* __restrict__ attn_out, float* __restrict__ ent_part) {
    const int S = 1024, D = 1024;
    const float LOG2E = 1.4426950408889634f;
    const float LN2 = 0.6931471805599453f;
    int flat = blockIdx.x + 16 * blockIdx.y;              // 512 blocks
    int vid = (flat & 7) * 64 + (flat >> 3);
    int qt = vid & 15;
    int bh = vid >> 4;
    int b = bh >> 4, h = bh & 15;
    int tid = threadIdx.x;
    int wave = tid >> 6, lane = tid & 63;
    int lr = lane & 15, lk = lane >> 4;

    __shared__ unsigned short Ks[128 * 64];    // [n][d] swizzled, 16KB
    __shared__ unsigned short Vts[64 * 128];   // [d][pi(n)] swizzled, 16KB
    __shared__ float wpart[4];

    const float rbl = res_bias[h] * LOG2E;
    const float c1 = 0.125f * LOG2E;
    const unsigned short* qg = qb + (size_t)(b * S + qt * 64) * D + h * 64;
    const unsigned short* kg = kb + (size_t)(b * S) * D + h * 64;
    const unsigned short* vtg = vtb + (size_t)bh * 64 * 1024;

    // Q fragments: loop-invariant, wave-private rows -> registers, straight from global
    ushort8 qf[2];
#pragma unroll
    for (int ks = 0; ks < 2; ++ks)
        qf[ks] = *(const ushort8*)(qg + (size_t)(wave * 16 + lr) * D + (ks * 4 + lk) * 8);

    // prefetch KV tile 0 into registers
    ushort8 kr[4], vr[4];
#pragma unroll
    for (int i = 0; i < 4; ++i) {
        int c = tid + 256 * i;
        kr[i] = *(const ushort8*)(kg + (size_t)(c >> 3) * D + (c & 7) * 8);
        vr[i] = *(const ushort8*)(vtg + (size_t)(c >> 4) * 1024 + (c & 15) * 8);
    }

    f32x4 o[4] = {};
    float l_ = 0.f, ps_ = 0.f;   // per-lane row stats (log2-domain ps), row q = wave*16+lr

    for (int kt = 0; kt < 8; ++kt) {
        __syncthreads();
        // write prefetched tile to LDS (K swizzled; V permuted pi + swizzled)
#pragma unroll
        for (int i = 0; i < 4; ++i) {
            int c = tid + 256 * i;
            int r1 = c >> 3, d1 = c & 7;
            *(ushort8*)&Ks[r1 * 64 + ((d1 ^ (r1 & 7)) * 8)] = kr[i];
            int r2 = c >> 4, d2 = c & 15;   // d-row, 8-n chunk (n = 8*d2..8*d2+7)
            int b0 = 32 * (d2 >> 2) + 16 * (d2 & 1) + 4 * ((d2 >> 1) & 1);
            int b1 = b0 + 8;
            ushort4 lo, hi;
            lo.x = vr[i][0]; lo.y = vr[i][1]; lo.z = vr[i][2]; lo.w = vr[i][3];
            hi.x = vr[i][4]; hi.y = vr[i][5]; hi.z = vr[i][6]; hi.w = vr[i][7];
            *(ushort4*)&Vts[r2 * 128 + (((b0 >> 3) ^ (r2 & 7)) * 8) + (b0 & 7)] = lo;
            *(ushort4*)&Vts[r2 * 128 + (((b1 >> 3) ^ (r2 & 7)) * 8) + (b1 & 7)] = hi;
        }
        __syncthreads();

        // issue next tile's loads (in flight under compute)
        if (kt < 7) {
#pragma unroll
            for (int i = 0; i < 4; ++i) {
                int c = tid + 256 * i;
                kr[i] = *(const ushort8*)(kg + (size_t)((kt + 1) * 128 + (c >> 3)) * D + (c & 7) * 8);
                vr[i] = *(const ushort8*)(vtg + (size_t)(c >> 4) * 1024 + (kt + 1) * 128 + (c & 15) * 8);
            }
        }

        // S^T = K Q^T: lane holds q = wave*16+lr, P[q][n=16*fj+4*lk+r] in sf[fj][r]
        f32x4 sf[8] = {};
        __builtin_amdgcn_s_setprio(1);
#pragma unroll
        for (int ks = 0; ks < 2; ++ks) {
#pragma unroll
            for (int fj = 0; fj < 8; ++fj) {
                ushort8 kf = *(const ushort8*)&Ks[(fj * 16 + lr) * 64 + (((ks * 4 + lk) ^ (lr & 7)) * 8)];
                sf[fj] = mfma16(kf, qf[ks], sf[fj]);   // A=K, B=Q  -> S^T
            }
        }
        __builtin_amdgcn_s_setprio(0);

        // exp2-domain fixed-shift softmax: t = s*log2e, p = 2^t (exact, |s| < ~3)
        float pl = 0.f, ps = 0.f;
#pragma unroll
        for (int fj = 0; fj < 8; ++fj)
#pragma unroll
            for (int r = 0; r < 4; ++r) {
                float t = sf[fj][r] * c1 + rbl;
                float pe = __builtin_amdgcn_exp2f(t);
                pl += pe; ps = fmaf(pe, t, ps);
                sf[fj][r] = pe;
            }
        // row-sum across the 4 lk replicas
        pl += __shfl_xor(pl, 16, 64); pl += __shfl_xor(pl, 32, 64);
        ps += __shfl_xor(ps, 16, 64); ps += __shfl_xor(ps, 32, 64);
        l_ += pl; ps_ += ps;

        // O += P V: A-frag packed directly from this lane's sf (k-slot (lk,p) holds
        // n = 16*(2ks+(p>>2)) + 4*lk + (p&3), matching Vts' pi layout).
        __builtin_amdgcn_s_setprio(1);
#pragma unroll
        for (int ks = 0; ks < 4; ++ks) {
            ushort8 ap;
            ap[0] = f2bf(sf[2 * ks][0]);     ap[1] = f2bf(sf[2 * ks][1]);
            ap[2] = f2bf(sf[2 * ks][2]);     ap[3] = f2bf(sf[2 * ks][3]);
            ap[4] = f2bf(sf[2 * ks + 1][0]); ap[5] = f2bf(sf[2 * ks + 1][1]);
            ap[6] = f2bf(sf[2 * ks + 1][2]); ap[7] = f2bf(sf[2 * ks + 1][3]);
#pragma unroll
            for (int fd = 0; fd < 4; ++fd) {
                ushort8 bv8 = *(const ushort8*)&Vts[(fd * 16 + lr) * 128 + (((ks * 4 + lk) ^ (lr & 7)) * 8)];
                o[fd] = mfma16(ap, bv8, o[fd]);
            }
        }
        __builtin_amdgcn_s_setprio(0);
    }

    // epilogue: O rows are q = wave*16 + lk*4 + r; stats live at lane lr = row
    float linv = 1.f / l_;
    float ent_row = __logf(l_) - LN2 * ps_ * linv;
    float linv_r[4];
#pragma unroll
    for (int r = 0; r < 4; ++r) linv_r[r] = __shfl(linv, lk * 4 + r, 64);
#pragma unroll
    for (int r = 0; r < 4; ++r) {
        int row = b * S + qt * 64 + wave * 16 + lk * 4 + r;
#pragma unroll
        for (int fd = 0; fd < 4; ++fd) {
            int col = h * 64 + fd * 16 + lr;
            attn_out[(size_t)row * D + col] = f2bf(o[fd][r] * linv_r[r]);
        }
    }
    // entropy: sum rows 0..15 within each 16-lane group (lk replicas identical)
    float es = ent_row;
    es += __shfl_xor(es, 1, 64);
    es += __shfl_xor(es, 2, 64);
    es += __shfl_xor(es, 4, 64);
    es += __shfl_xor(es, 8, 64);
    if (lane == 0) wpart[wave] = es;
    __syncthreads();
    if (tid == 0) ent_part[bh * 16 + qt] = wpart[0] + wpart[1] + wpart[2] + wpart[3];
}

extern "C" void kernel_launch(void* const* d_in, const int* in_sizes, int n_in,
                              void* d_out, int out_size, void* d_ws, size_t ws_size,
                              hipStream_t stream) {
    const float* x  = (const float*)d_in[0];
    const float* wq = (const float*)d_in[1];
    const float* bq = (const float*)d_in[2];
    const float* wk = (const float*)d_in[3];
    const float* bk = (const float*)d_in[4];
    const float* wv = (const float*)d_in[5];
    const float* bv = (const float*)d_in[6];
    const float* wo = (const float*)d_in[7];
    const float* bo = (const float*)d_in[8];
    const float* rbias = (const float*)d_in[9];

    char* ws = (char*)d_ws;
    unsigned short* xb  = (unsigned short*)(ws);                      // 4 MB
    unsigned short* wqb = (unsigned short*)(ws + ((size_t)4 << 20));  // 2 MB
    unsigned short* wkb = (unsigned short*)(ws + ((size_t)6 << 20));
    unsigned short* wvb = (unsigned short*)(ws + ((size_t)8 << 20));
    unsigned short* wob = (unsigned short*)(ws + ((size_t)10 << 20));
    unsigned short* qbf = (unsigned short*)(ws + ((size_t)12 << 20));
    unsigned short* kbf = (unsigned short*)(ws + ((size_t)16 << 20));
    unsigned short* vtb = (unsigned short*)(ws + ((size_t)20 << 20)); // V^T [32][64][1024]
    unsigned short* aob = (unsigned short*)(ws + ((size_t)24 << 20));
    float* ent_part = (float*)(ws + ((size_t)28 << 20));

    float* out = (float*)d_out;
    float* out_ent = out + (size_t)2 * 1024 * 1024;
    float* out_iters = out_ent + 32;

    cvt_all_kernel<<<dim3(3072), dim3(256), 0, stream>>>(x, wq, wk, wv, wo, xb);
    gemm_qkv<<<dim3(16, 16, 3), dim3(256), 0, stream>>>(xb, wqb, wkb, wvb, bq, bk, bv, qbf, kbf, vtb);
    attn_kernel<<<dim3(16, 32), dim3(256), 0, stream>>>(qbf, kbf, vtb, rbias, aob, ent_part);
    gemm_out<<<dim3(32, 16), dim3(256), 0, stream>>>(aob, wob, bo, out, ent_part, out_ent, out_iters);
}